// Round 3
// baseline (40.688 us; speedup 1.0000x reference)
//
#include <hip/hip_runtime.h>
#include <hip/hip_bf16.h>
#include <hip/hip_cooperative_groups.h>

namespace cg = cooperative_groups;

#define KCLS 8192
#define DFEAT 64
#define BATCH_N 16384
#define LAMB 0.01
#define LAMB1 10.0

constexpr int NBLK = 256;   // cooperative grid: 256 blocks x 4 waves = 1024 waves

// ws layout (floats): [0 .. NBLK*64)        : per-block S partial 64-vectors
//                     [NBLK*64 .. +NBLK)    : per-block center-loss partial scalars
__global__ __launch_bounds__(256) void illoss_coop(const int* __restrict__ y,
                                                   const float* __restrict__ feat,
                                                   const float* __restrict__ centers,
                                                   float* __restrict__ ws,
                                                   float* __restrict__ out) {
    const int tid  = threadIdx.x;
    const int lane = tid & 63;
    const int wave = tid >> 6;
    const int blk  = blockIdx.x;
    const int gwid = blk * 4 + wave;               // 0..1023
    const float4* __restrict__ centers4 = (const float4*)centers;
    const float4* __restrict__ feat4    = (const float4*)feat;

    __shared__ float sacc[4][16][4];
    __shared__ float wacc[4];
    __shared__ float fin[4][64];

    // ---- issue y loads early (independent of S phase) ----
    const int base = gwid * 16;                    // 16 batch items per wave
    int cls[4];
    #pragma unroll
    for (int it = 0; it < 4; ++it) cls[it] = y[base + it * 4 + (lane >> 4)];

    // ---- S = sum_k centers[k]/||centers[k]|| : 8 rows per wave ----
    // Wave loads 64 float4 = 4 consecutive rows; 16-lane group g holds row base+g.
    float ax = 0.f, ay = 0.f, az = 0.f, aw = 0.f;
    #pragma unroll
    for (int it = 0; it < 2; ++it) {
        const int row0 = gwid * 8 + it * 4;
        float4 v = centers4[row0 * 16 + lane];
        float ss = v.x * v.x + v.y * v.y + v.z * v.z + v.w * v.w;
        ss += __shfl_xor(ss, 1, 64);
        ss += __shfl_xor(ss, 2, 64);
        ss += __shfl_xor(ss, 4, 64);
        ss += __shfl_xor(ss, 8, 64);               // per 16-lane group: ||c||^2
        float inv = __frsqrt_rn(ss);
        ax += v.x * inv; ay += v.y * inv; az += v.z * inv; aw += v.w * inv;
    }
    ax += __shfl_xor(ax, 16, 64); ay += __shfl_xor(ay, 16, 64);
    az += __shfl_xor(az, 16, 64); aw += __shfl_xor(aw, 16, 64);
    ax += __shfl_xor(ax, 32, 64); ay += __shfl_xor(ay, 32, 64);
    az += __shfl_xor(az, 32, 64); aw += __shfl_xor(aw, 32, 64);
    if (lane < 16) {
        sacc[wave][lane][0] = ax; sacc[wave][lane][1] = ay;
        sacc[wave][lane][2] = az; sacc[wave][lane][3] = aw;
    }

    // ---- loss_cen partial: 16 items per wave ----
    float acc = 0.f;
    #pragma unroll
    for (int it = 0; it < 4; ++it) {
        float4 f = feat4[(base + it * 4) * 16 + lane];
        float4 c = centers4[cls[it] * 16 + (lane & 15)];
        float dx = f.x - c.x, dy = f.y - c.y, dz = f.z - c.z, dw = f.w - c.w;
        acc += dx * dx + dy * dy + dz * dz + dw * dw;
    }
    acc += __shfl_xor(acc, 1, 64);
    acc += __shfl_xor(acc, 2, 64);
    acc += __shfl_xor(acc, 4, 64);
    acc += __shfl_xor(acc, 8, 64);
    acc += __shfl_xor(acc, 16, 64);
    acc += __shfl_xor(acc, 32, 64);
    if (lane == 0) wacc[wave] = acc;
    __syncthreads();

    // ---- per-block partials -> ws ----
    if (tid < 64) {
        const int c = tid;
        float s = sacc[0][c >> 2][c & 3] + sacc[1][c >> 2][c & 3]
                + sacc[2][c >> 2][c & 3] + sacc[3][c >> 2][c & 3];
        ws[blk * 64 + c] = s;
    }
    if (tid == 0) ws[NBLK * 64 + blk] = wacc[0] + wacc[1] + wacc[2] + wacc[3];

    cg::this_grid().sync();

    // ---- block 0: final reduction ----
    if (blk == 0) {
        const int c = tid & 63, w = tid >> 6;
        float s = 0.f;
        #pragma unroll 8
        for (int b = w; b < NBLK; b += 4) s += ws[b * 64 + c];
        fin[w][c] = s;
        __syncthreads();
        if (wave == 0) {
            float S = fin[0][lane] + fin[1][lane] + fin[2][lane] + fin[3][lane];
            float s2 = S * S;
            s2 += __shfl_xor(s2, 1, 64);
            s2 += __shfl_xor(s2, 2, 64);
            s2 += __shfl_xor(s2, 4, 64);
            s2 += __shfl_xor(s2, 8, 64);
            s2 += __shfl_xor(s2, 16, 64);
            s2 += __shfl_xor(s2, 32, 64);
            const float* cw = ws + NBLK * 64;
            float cacc = cw[lane] + cw[lane + 64] + cw[lane + 128] + cw[lane + 192];
            cacc += __shfl_xor(cacc, 1, 64);
            cacc += __shfl_xor(cacc, 2, 64);
            cacc += __shfl_xor(cacc, 4, 64);
            cacc += __shfl_xor(cacc, 8, 64);
            cacc += __shfl_xor(cacc, 16, 64);
            cacc += __shfl_xor(cacc, 32, 64);
            if (lane == 0) {
                double loss_cen = 0.5 * (double)cacc / (double)BATCH_N;
                double loss_ang = (double)s2 - (double)KCLS + (double)KCLS * (double)(KCLS - 1);
                out[0] = (float)(LAMB * (loss_cen + LAMB1 * loss_ang));
            }
        }
    }
}

extern "C" void kernel_launch(void* const* d_in, const int* in_sizes, int n_in,
                              void* d_out, int out_size, void* d_ws, size_t ws_size,
                              hipStream_t stream) {
    const int*   y       = (const int*)d_in[0];
    const float* feat    = (const float*)d_in[1];
    const float* centers = (const float*)d_in[2];
    float* out = (float*)d_out;
    float* ws  = (float*)d_ws;

    void* args[] = {(void*)&y, (void*)&feat, (void*)&centers, (void*)&ws, (void*)&out};
    hipLaunchCooperativeKernel((void*)illoss_coop, dim3(NBLK), dim3(256), args, 0, stream);
}

// Round 5
// 25.931 us; speedup vs baseline: 1.5691x; 1.5691x over previous
//
#include <hip/hip_runtime.h>
#include <hip/hip_bf16.h>

#define KCLS 8192
#define DFEAT 64
#define BATCH_N 16384
#define LAMB 0.01
#define LAMB1 10.0

constexpr int NBLK = 256;

// ws layout: sp[NBLK*64] floats | cp[NBLK] floats | cnt (1 uint)
// cnt is hipMemsetAsync'd to 0 at the start of every call; each block
// increments it after publishing partials; the LAST block (old == NBLK-1)
// performs the final reduction. No block ever waits -> no hang possible.
__global__ __launch_bounds__(256) void illoss_onepass(const int* __restrict__ y,
                                                      const float* __restrict__ feat,
                                                      const float* __restrict__ centers,
                                                      float* __restrict__ sp,
                                                      float* __restrict__ cp,
                                                      unsigned* __restrict__ cnt,
                                                      float* __restrict__ out) {
    const int tid  = threadIdx.x;
    const int lane = tid & 63;
    const int wave = tid >> 6;
    const int blk  = blockIdx.x;
    const int gwid = blk * 4 + wave;               // 0..1023
    const float4* __restrict__ centers4 = (const float4*)centers;
    const float4* __restrict__ feat4    = (const float4*)feat;

    __shared__ float sacc[4][16][4];
    __shared__ float wacc[4];
    __shared__ float fin[4][64];
    __shared__ unsigned is_last;

    // ---- issue y loads early ----
    const int base = gwid * 16;                    // 16 batch items per wave
    int cls[4];
    #pragma unroll
    for (int it = 0; it < 4; ++it) cls[it] = y[base + it * 4 + (lane >> 4)];

    // ---- S partial: 8 rows per wave (wave loads 4 rows per float4 iter) ----
    float ax = 0.f, ay = 0.f, az = 0.f, aw = 0.f;
    #pragma unroll
    for (int it = 0; it < 2; ++it) {
        const int row0 = gwid * 8 + it * 4;
        float4 v = centers4[row0 * 16 + lane];
        float ss = v.x * v.x + v.y * v.y + v.z * v.z + v.w * v.w;
        ss += __shfl_xor(ss, 1, 64);
        ss += __shfl_xor(ss, 2, 64);
        ss += __shfl_xor(ss, 4, 64);
        ss += __shfl_xor(ss, 8, 64);               // per 16-lane group: ||c||^2
        float inv = __frsqrt_rn(ss);
        ax += v.x * inv; ay += v.y * inv; az += v.z * inv; aw += v.w * inv;
    }
    ax += __shfl_xor(ax, 16, 64); ay += __shfl_xor(ay, 16, 64);
    az += __shfl_xor(az, 16, 64); aw += __shfl_xor(aw, 16, 64);
    ax += __shfl_xor(ax, 32, 64); ay += __shfl_xor(ay, 32, 64);
    az += __shfl_xor(az, 32, 64); aw += __shfl_xor(aw, 32, 64);
    if (lane < 16) {
        sacc[wave][lane][0] = ax; sacc[wave][lane][1] = ay;
        sacc[wave][lane][2] = az; sacc[wave][lane][3] = aw;
    }

    // ---- cen partial: 16 items per wave ----
    float acc = 0.f;
    #pragma unroll
    for (int it = 0; it < 4; ++it) {
        float4 f = feat4[(base + it * 4) * 16 + lane];
        float4 c = centers4[cls[it] * 16 + (lane & 15)];
        float dx = f.x - c.x, dy = f.y - c.y, dz = f.z - c.z, dw = f.w - c.w;
        acc += dx * dx + dy * dy + dz * dz + dw * dw;
    }
    acc += __shfl_xor(acc, 1, 64);
    acc += __shfl_xor(acc, 2, 64);
    acc += __shfl_xor(acc, 4, 64);
    acc += __shfl_xor(acc, 8, 64);
    acc += __shfl_xor(acc, 16, 64);
    acc += __shfl_xor(acc, 32, 64);
    if (lane == 0) wacc[wave] = acc;
    __syncthreads();

    // ---- publish per-block partials ----
    if (tid < 64) {
        float s = sacc[0][tid >> 2][tid & 3] + sacc[1][tid >> 2][tid & 3]
                + sacc[2][tid >> 2][tid & 3] + sacc[3][tid >> 2][tid & 3];
        sp[blk * 64 + tid] = s;
    }
    if (tid == 0) cp[blk] = wacc[0] + wacc[1] + wacc[2] + wacc[3];
    __syncthreads();

    // ---- last-block-done: no waiting, the final arriver finalizes ----
    if (tid == 0) {
        __threadfence();  // release: partials visible device-wide before count
        unsigned old = __hip_atomic_fetch_add(cnt, 1u, __ATOMIC_ACQ_REL,
                                              __HIP_MEMORY_SCOPE_AGENT);
        is_last = (old == NBLK - 1) ? 1u : 0u;
    }
    __syncthreads();
    if (!is_last) return;
    __threadfence();  // acquire: see all blocks' partials

    // ---- final reduction (256 threads of the last block) ----
    const int c = tid & 63;
    float s0 = 0.f, s1 = 0.f, s2v = 0.f, s3 = 0.f;
    #pragma unroll
    for (int b = wave; b < NBLK; b += 16) {
        s0  += sp[(b + 0) * 64 + c];
        s1  += sp[(b + 4) * 64 + c];
        s2v += sp[(b + 8) * 64 + c];
        s3  += sp[(b + 12) * 64 + c];
    }
    fin[wave][c] = (s0 + s1) + (s2v + s3);
    __syncthreads();
    if (wave == 0) {
        float S = fin[0][lane] + fin[1][lane] + fin[2][lane] + fin[3][lane];
        float s2 = S * S;
        s2 += __shfl_xor(s2, 1, 64);
        s2 += __shfl_xor(s2, 2, 64);
        s2 += __shfl_xor(s2, 4, 64);
        s2 += __shfl_xor(s2, 8, 64);
        s2 += __shfl_xor(s2, 16, 64);
        s2 += __shfl_xor(s2, 32, 64);
        float cacc = cp[lane] + cp[lane + 64] + cp[lane + 128] + cp[lane + 192];
        cacc += __shfl_xor(cacc, 1, 64);
        cacc += __shfl_xor(cacc, 2, 64);
        cacc += __shfl_xor(cacc, 4, 64);
        cacc += __shfl_xor(cacc, 8, 64);
        cacc += __shfl_xor(cacc, 16, 64);
        cacc += __shfl_xor(cacc, 32, 64);
        if (lane == 0) {
            double loss_cen = 0.5 * (double)cacc / (double)BATCH_N;
            double loss_ang = (double)s2 - (double)KCLS + (double)KCLS * (double)(KCLS - 1);
            out[0] = (float)(LAMB * (loss_cen + LAMB1 * loss_ang));
        }
    }
}

extern "C" void kernel_launch(void* const* d_in, const int* in_sizes, int n_in,
                              void* d_out, int out_size, void* d_ws, size_t ws_size,
                              hipStream_t stream) {
    const int*   y       = (const int*)d_in[0];
    const float* feat    = (const float*)d_in[1];
    const float* centers = (const float*)d_in[2];
    float* out = (float*)d_out;
    float* sp  = (float*)d_ws;                       // NBLK*64 floats
    float* cp  = sp + NBLK * 64;                     // NBLK floats
    unsigned* cnt = (unsigned*)(cp + NBLK);          // 1 uint

    hipMemsetAsync(cnt, 0, sizeof(unsigned), stream);
    illoss_onepass<<<NBLK, 256, 0, stream>>>(y, feat, centers, sp, cp, cnt, out);
}

// Round 6
// 25.569 us; speedup vs baseline: 1.5913x; 1.0141x over previous
//
#include <hip/hip_runtime.h>
#include <hip/hip_bf16.h>

#define KCLS 8192
#define DFEAT 64
#define BATCH_N 16384
#define LAMB 0.01
#define LAMB1 10.0

constexpr int NBLK = 256;

__global__ __launch_bounds__(64) void zero_cnt(unsigned* __restrict__ cnt) {
    if (threadIdx.x == 0) cnt[0] = 0u;
}

// ws layout: sp[NBLK*64] floats | cp[NBLK] floats | cnt (1 uint)
// cnt is zeroed by zero_cnt each call; each block increments it after
// publishing partials; the LAST block (old == NBLK-1) does the final
// reduction. No block ever waits -> no hang possible.
__global__ __launch_bounds__(256) void illoss_onepass(const int* __restrict__ y,
                                                      const float* __restrict__ feat,
                                                      const float* __restrict__ centers,
                                                      float* __restrict__ sp,
                                                      float* __restrict__ cp,
                                                      unsigned* __restrict__ cnt,
                                                      float* __restrict__ out) {
    const int tid  = threadIdx.x;
    const int lane = tid & 63;
    const int wave = tid >> 6;
    const int blk  = blockIdx.x;
    const int gwid = blk * 4 + wave;               // 0..1023
    const float4* __restrict__ centers4 = (const float4*)centers;
    const float4* __restrict__ feat4    = (const float4*)feat;

    __shared__ float sacc[4][16][4];
    __shared__ float wacc[4];
    __shared__ float fin[4][64];
    __shared__ unsigned is_last;

    // ---- issue y loads early ----
    const int base = gwid * 16;                    // 16 batch items per wave
    int cls[4];
    #pragma unroll
    for (int it = 0; it < 4; ++it) cls[it] = y[base + it * 4 + (lane >> 4)];

    // ---- S partial: 8 rows per wave (wave loads 4 rows per float4 iter) ----
    float ax = 0.f, ay = 0.f, az = 0.f, aw = 0.f;
    #pragma unroll
    for (int it = 0; it < 2; ++it) {
        const int row0 = gwid * 8 + it * 4;
        float4 v = centers4[row0 * 16 + lane];
        float ss = v.x * v.x + v.y * v.y + v.z * v.z + v.w * v.w;
        ss += __shfl_xor(ss, 1, 64);
        ss += __shfl_xor(ss, 2, 64);
        ss += __shfl_xor(ss, 4, 64);
        ss += __shfl_xor(ss, 8, 64);               // per 16-lane group: ||c||^2
        float inv = __frsqrt_rn(ss);
        ax += v.x * inv; ay += v.y * inv; az += v.z * inv; aw += v.w * inv;
    }
    ax += __shfl_xor(ax, 16, 64); ay += __shfl_xor(ay, 16, 64);
    az += __shfl_xor(az, 16, 64); aw += __shfl_xor(aw, 16, 64);
    ax += __shfl_xor(ax, 32, 64); ay += __shfl_xor(ay, 32, 64);
    az += __shfl_xor(az, 32, 64); aw += __shfl_xor(aw, 32, 64);
    if (lane < 16) {
        sacc[wave][lane][0] = ax; sacc[wave][lane][1] = ay;
        sacc[wave][lane][2] = az; sacc[wave][lane][3] = aw;
    }

    // ---- cen partial: 16 items per wave ----
    float acc = 0.f;
    #pragma unroll
    for (int it = 0; it < 4; ++it) {
        float4 f = feat4[(base + it * 4) * 16 + lane];
        float4 c = centers4[cls[it] * 16 + (lane & 15)];
        float dx = f.x - c.x, dy = f.y - c.y, dz = f.z - c.z, dw = f.w - c.w;
        acc += dx * dx + dy * dy + dz * dz + dw * dw;
    }
    acc += __shfl_xor(acc, 1, 64);
    acc += __shfl_xor(acc, 2, 64);
    acc += __shfl_xor(acc, 4, 64);
    acc += __shfl_xor(acc, 8, 64);
    acc += __shfl_xor(acc, 16, 64);
    acc += __shfl_xor(acc, 32, 64);
    if (lane == 0) wacc[wave] = acc;
    __syncthreads();

    // ---- publish per-block partials ----
    if (tid < 64) {
        float s = sacc[0][tid >> 2][tid & 3] + sacc[1][tid >> 2][tid & 3]
                + sacc[2][tid >> 2][tid & 3] + sacc[3][tid >> 2][tid & 3];
        sp[blk * 64 + tid] = s;
    }
    if (tid == 0) cp[blk] = wacc[0] + wacc[1] + wacc[2] + wacc[3];
    __syncthreads();

    // ---- last-block-done: no waiting, the final arriver finalizes ----
    if (tid == 0) {
        __threadfence();  // release: partials visible device-wide before count
        unsigned old = __hip_atomic_fetch_add(cnt, 1u, __ATOMIC_ACQ_REL,
                                              __HIP_MEMORY_SCOPE_AGENT);
        is_last = (old == NBLK - 1) ? 1u : 0u;
    }
    __syncthreads();
    if (!is_last) return;
    __threadfence();  // acquire: see all blocks' partials

    // ---- final reduction (256 threads of the last block) ----
    const int c = tid & 63;
    float s0 = 0.f, s1 = 0.f, s2v = 0.f, s3 = 0.f;
    #pragma unroll
    for (int b = wave; b < NBLK; b += 16) {
        s0  += sp[(b + 0) * 64 + c];
        s1  += sp[(b + 4) * 64 + c];
        s2v += sp[(b + 8) * 64 + c];
        s3  += sp[(b + 12) * 64 + c];
    }
    fin[wave][c] = (s0 + s1) + (s2v + s3);
    __syncthreads();
    if (wave == 0) {
        float S = fin[0][lane] + fin[1][lane] + fin[2][lane] + fin[3][lane];
        float s2 = S * S;
        s2 += __shfl_xor(s2, 1, 64);
        s2 += __shfl_xor(s2, 2, 64);
        s2 += __shfl_xor(s2, 4, 64);
        s2 += __shfl_xor(s2, 8, 64);
        s2 += __shfl_xor(s2, 16, 64);
        s2 += __shfl_xor(s2, 32, 64);
        float cacc = cp[lane] + cp[lane + 64] + cp[lane + 128] + cp[lane + 192];
        cacc += __shfl_xor(cacc, 1, 64);
        cacc += __shfl_xor(cacc, 2, 64);
        cacc += __shfl_xor(cacc, 4, 64);
        cacc += __shfl_xor(cacc, 8, 64);
        cacc += __shfl_xor(cacc, 16, 64);
        cacc += __shfl_xor(cacc, 32, 64);
        if (lane == 0) {
            double loss_cen = 0.5 * (double)cacc / (double)BATCH_N;
            double loss_ang = (double)s2 - (double)KCLS + (double)KCLS * (double)(KCLS - 1);
            out[0] = (float)(LAMB * (loss_cen + LAMB1 * loss_ang));
        }
    }
}

extern "C" void kernel_launch(void* const* d_in, const int* in_sizes, int n_in,
                              void* d_out, int out_size, void* d_ws, size_t ws_size,
                              hipStream_t stream) {
    const int*   y       = (const int*)d_in[0];
    const float* feat    = (const float*)d_in[1];
    const float* centers = (const float*)d_in[2];
    float* out = (float*)d_out;
    float* sp  = (float*)d_ws;                       // NBLK*64 floats
    float* cp  = sp + NBLK * 64;                     // NBLK floats
    unsigned* cnt = (unsigned*)(cp + NBLK);          // 1 uint

    zero_cnt<<<1, 64, 0, stream>>>(cnt);
    illoss_onepass<<<NBLK, 256, 0, stream>>>(y, feat, centers, sp, cp, cnt, out);
}

// Round 7
// 15.826 us; speedup vs baseline: 2.5710x; 1.6157x over previous
//
#include <hip/hip_runtime.h>
#include <hip/hip_bf16.h>

#define KCLS 8192
#define DFEAT 64
#define BATCH_N 16384
#define LAMB 0.01
#define LAMB1 10.0

constexpr int NBLK = 256;

__global__ __launch_bounds__(64) void zero_cnt(unsigned* __restrict__ cnt) {
    if (threadIdx.x == 0) cnt[0] = 0u;
}

#define AGENT_ST(p, v) __hip_atomic_store((p), (v), __ATOMIC_RELAXED, __HIP_MEMORY_SCOPE_AGENT)
#define AGENT_LD(p)    __hip_atomic_load((p), __ATOMIC_RELAXED, __HIP_MEMORY_SCOPE_AGENT)

// ws layout: sp[NBLK*64] floats | cp[NBLK] floats | cnt (1 uint)
// Fence-free last-block-done: partials are published with agent-scope relaxed
// stores (write-through to the coherence point, no L2 writeback), sequenced by
// __syncthreads()'s vmcnt(0) drain before a RELAXED agent fetch_add. The last
// arriver (old == NBLK-1) reads partials with agent-scope relaxed loads: all
// other blocks' stores completed (their barrier drained vmcnt) strictly before
// their increment, and RMW atomicity on cnt orders the increments, so the
// last arriver's bypassing loads must observe every partial. No fences, no
// waiting -> no L2 writebacks, no hang possible.
__global__ __launch_bounds__(256) void illoss_onepass(const int* __restrict__ y,
                                                      const float* __restrict__ feat,
                                                      const float* __restrict__ centers,
                                                      float* __restrict__ sp,
                                                      float* __restrict__ cp,
                                                      unsigned* __restrict__ cnt,
                                                      float* __restrict__ out) {
    const int tid  = threadIdx.x;
    const int lane = tid & 63;
    const int wave = tid >> 6;
    const int blk  = blockIdx.x;
    const int gwid = blk * 4 + wave;               // 0..1023
    const float4* __restrict__ centers4 = (const float4*)centers;
    const float4* __restrict__ feat4    = (const float4*)feat;

    __shared__ float sacc[4][16][4];
    __shared__ float wacc[4];
    __shared__ float fin[4][64];
    __shared__ unsigned is_last;

    // ---- issue y loads early ----
    const int base = gwid * 16;                    // 16 batch items per wave
    int cls[4];
    #pragma unroll
    for (int it = 0; it < 4; ++it) cls[it] = y[base + it * 4 + (lane >> 4)];

    // ---- S partial: 8 rows per wave (wave loads 4 rows per float4 iter) ----
    float ax = 0.f, ay = 0.f, az = 0.f, aw = 0.f;
    #pragma unroll
    for (int it = 0; it < 2; ++it) {
        const int row0 = gwid * 8 + it * 4;
        float4 v = centers4[row0 * 16 + lane];
        float ss = v.x * v.x + v.y * v.y + v.z * v.z + v.w * v.w;
        ss += __shfl_xor(ss, 1, 64);
        ss += __shfl_xor(ss, 2, 64);
        ss += __shfl_xor(ss, 4, 64);
        ss += __shfl_xor(ss, 8, 64);               // per 16-lane group: ||c||^2
        float inv = __frsqrt_rn(ss);
        ax += v.x * inv; ay += v.y * inv; az += v.z * inv; aw += v.w * inv;
    }
    ax += __shfl_xor(ax, 16, 64); ay += __shfl_xor(ay, 16, 64);
    az += __shfl_xor(az, 16, 64); aw += __shfl_xor(aw, 16, 64);
    ax += __shfl_xor(ax, 32, 64); ay += __shfl_xor(ay, 32, 64);
    az += __shfl_xor(az, 32, 64); aw += __shfl_xor(aw, 32, 64);
    if (lane < 16) {
        sacc[wave][lane][0] = ax; sacc[wave][lane][1] = ay;
        sacc[wave][lane][2] = az; sacc[wave][lane][3] = aw;
    }

    // ---- cen partial: 16 items per wave ----
    float acc = 0.f;
    #pragma unroll
    for (int it = 0; it < 4; ++it) {
        float4 f = feat4[(base + it * 4) * 16 + lane];
        float4 c = centers4[cls[it] * 16 + (lane & 15)];
        float dx = f.x - c.x, dy = f.y - c.y, dz = f.z - c.z, dw = f.w - c.w;
        acc += dx * dx + dy * dy + dz * dz + dw * dw;
    }
    acc += __shfl_xor(acc, 1, 64);
    acc += __shfl_xor(acc, 2, 64);
    acc += __shfl_xor(acc, 4, 64);
    acc += __shfl_xor(acc, 8, 64);
    acc += __shfl_xor(acc, 16, 64);
    acc += __shfl_xor(acc, 32, 64);
    if (lane == 0) wacc[wave] = acc;
    __syncthreads();

    // ---- publish per-block partials (agent-scope, bypassing local L2) ----
    if (tid < 64) {
        float s = sacc[0][tid >> 2][tid & 3] + sacc[1][tid >> 2][tid & 3]
                + sacc[2][tid >> 2][tid & 3] + sacc[3][tid >> 2][tid & 3];
        AGENT_ST(&sp[blk * 64 + tid], s);
    }
    if (tid == 0) AGENT_ST(&cp[blk], wacc[0] + wacc[1] + wacc[2] + wacc[3]);
    __syncthreads();  // drains vmcnt: all agent stores of this block completed

    // ---- last-block-done: relaxed far-atomic, no fences ----
    if (tid == 0) {
        unsigned old = __hip_atomic_fetch_add(cnt, 1u, __ATOMIC_RELAXED,
                                              __HIP_MEMORY_SCOPE_AGENT);
        is_last = (old == NBLK - 1) ? 1u : 0u;
    }
    __syncthreads();
    if (!is_last) return;

    // ---- final reduction (256 threads of the last block) ----
    const int c = tid & 63;
    float s[8] = {0.f, 0.f, 0.f, 0.f, 0.f, 0.f, 0.f, 0.f};
    #pragma unroll
    for (int k = 0; k < 64; ++k) {
        const int b = wave + 4 * k;               // covers all b ≡ wave (mod 4)
        s[k & 7] += AGENT_LD(&sp[b * 64 + c]);
    }
    fin[wave][c] = ((s[0] + s[1]) + (s[2] + s[3])) + ((s[4] + s[5]) + (s[6] + s[7]));
    __syncthreads();
    if (wave == 0) {
        float S = fin[0][lane] + fin[1][lane] + fin[2][lane] + fin[3][lane];
        float s2 = S * S;
        s2 += __shfl_xor(s2, 1, 64);
        s2 += __shfl_xor(s2, 2, 64);
        s2 += __shfl_xor(s2, 4, 64);
        s2 += __shfl_xor(s2, 8, 64);
        s2 += __shfl_xor(s2, 16, 64);
        s2 += __shfl_xor(s2, 32, 64);
        float c0 = AGENT_LD(&cp[lane]);
        float c1 = AGENT_LD(&cp[lane + 64]);
        float c2 = AGENT_LD(&cp[lane + 128]);
        float c3 = AGENT_LD(&cp[lane + 192]);
        float cacc = (c0 + c1) + (c2 + c3);
        cacc += __shfl_xor(cacc, 1, 64);
        cacc += __shfl_xor(cacc, 2, 64);
        cacc += __shfl_xor(cacc, 4, 64);
        cacc += __shfl_xor(cacc, 8, 64);
        cacc += __shfl_xor(cacc, 16, 64);
        cacc += __shfl_xor(cacc, 32, 64);
        if (lane == 0) {
            double loss_cen = 0.5 * (double)cacc / (double)BATCH_N;
            double loss_ang = (double)s2 - (double)KCLS + (double)KCLS * (double)(KCLS - 1);
            out[0] = (float)(LAMB * (loss_cen + LAMB1 * loss_ang));
        }
    }
}

extern "C" void kernel_launch(void* const* d_in, const int* in_sizes, int n_in,
                              void* d_out, int out_size, void* d_ws, size_t ws_size,
                              hipStream_t stream) {
    const int*   y       = (const int*)d_in[0];
    const float* feat    = (const float*)d_in[1];
    const float* centers = (const float*)d_in[2];
    float* out = (float*)d_out;
    float* sp  = (float*)d_ws;                       // NBLK*64 floats
    float* cp  = sp + NBLK * 64;                     // NBLK floats
    unsigned* cnt = (unsigned*)(cp + NBLK);          // 1 uint

    zero_cnt<<<1, 64, 0, stream>>>(cnt);
    illoss_onepass<<<NBLK, 256, 0, stream>>>(y, feat, centers, sp, cp, cnt, out);
}

// Round 9
// 13.162 us; speedup vs baseline: 3.0914x; 1.2024x over previous
//
#include <hip/hip_runtime.h>
#include <hip/hip_bf16.h>

#define KCLS 8192
#define DFEAT 64
#define BATCH_N 16384
#define LAMB 0.01
#define LAMB1 10.0

constexpr int NBLK = 256;

// ws layout: sp[NBLK*64] floats | cp[NBLK] floats
// Two-node graph: fused partials kernel -> tiny finalize kernel. The kernel
// boundary is the cross-XCD sync (measured cheaper than any in-kernel
// protocol: grid.sync +30us, fenced counter +14us, relaxed counter +4us).
__global__ __launch_bounds__(256) void illoss_partials(const int* __restrict__ y,
                                                       const float* __restrict__ feat,
                                                       const float* __restrict__ centers,
                                                       float* __restrict__ sp,
                                                       float* __restrict__ cp) {
    const int tid  = threadIdx.x;
    const int lane = tid & 63;
    const int wave = tid >> 6;
    const int blk  = blockIdx.x;
    const int gwid = blk * 4 + wave;               // 0..1023
    const float4* __restrict__ centers4 = (const float4*)centers;
    const float4* __restrict__ feat4    = (const float4*)feat;

    __shared__ float sacc[4][16][4];
    __shared__ float wacc[4];

    // ---- issue y loads early ----
    const int base = gwid * 16;                    // 16 batch items per wave
    int cls[4];
    #pragma unroll
    for (int it = 0; it < 4; ++it) cls[it] = y[base + it * 4 + (lane >> 4)];

    // ---- S partial: 8 rows per wave (wave loads 4 rows per float4 iter) ----
    float ax = 0.f, ay = 0.f, az = 0.f, aw = 0.f;
    #pragma unroll
    for (int it = 0; it < 2; ++it) {
        const int row0 = gwid * 8 + it * 4;
        float4 v = centers4[row0 * 16 + lane];
        float ss = v.x * v.x + v.y * v.y + v.z * v.z + v.w * v.w;
        ss += __shfl_xor(ss, 1, 64);
        ss += __shfl_xor(ss, 2, 64);
        ss += __shfl_xor(ss, 4, 64);
        ss += __shfl_xor(ss, 8, 64);               // per 16-lane group: ||c||^2
        float inv = __frsqrt_rn(ss);
        ax += v.x * inv; ay += v.y * inv; az += v.z * inv; aw += v.w * inv;
    }
    ax += __shfl_xor(ax, 16, 64); ay += __shfl_xor(ay, 16, 64);
    az += __shfl_xor(az, 16, 64); aw += __shfl_xor(aw, 16, 64);
    ax += __shfl_xor(ax, 32, 64); ay += __shfl_xor(ay, 32, 64);
    az += __shfl_xor(az, 32, 64); aw += __shfl_xor(aw, 32, 64);
    if (lane < 16) {
        sacc[wave][lane][0] = ax; sacc[wave][lane][1] = ay;
        sacc[wave][lane][2] = az; sacc[wave][lane][3] = aw;
    }

    // ---- cen partial: 16 items per wave ----
    float acc = 0.f;
    #pragma unroll
    for (int it = 0; it < 4; ++it) {
        float4 f = feat4[(base + it * 4) * 16 + lane];
        float4 c = centers4[cls[it] * 16 + (lane & 15)];
        float dx = f.x - c.x, dy = f.y - c.y, dz = f.z - c.z, dw = f.w - c.w;
        acc += dx * dx + dy * dy + dz * dz + dw * dw;
    }
    acc += __shfl_xor(acc, 1, 64);
    acc += __shfl_xor(acc, 2, 64);
    acc += __shfl_xor(acc, 4, 64);
    acc += __shfl_xor(acc, 8, 64);
    acc += __shfl_xor(acc, 16, 64);
    acc += __shfl_xor(acc, 32, 64);
    if (lane == 0) wacc[wave] = acc;
    __syncthreads();

    // ---- publish per-block partials (plain stores; kernel boundary syncs) ----
    if (tid < 64) {
        float s = sacc[0][tid >> 2][tid & 3] + sacc[1][tid >> 2][tid & 3]
                + sacc[2][tid >> 2][tid & 3] + sacc[3][tid >> 2][tid & 3];
        sp[blk * 64 + tid] = s;
    }
    if (tid == 0) cp[blk] = wacc[0] + wacc[1] + wacc[2] + wacc[3];
}

// Single-wave finalize: float4 loads of sp (64KB), shuffle-only reduction.
__global__ __launch_bounds__(64) void illoss_final(const float* __restrict__ sp,
                                                   const float* __restrict__ cp,
                                                   float* __restrict__ out) {
    const int l = threadIdx.x;
    const float4* __restrict__ sp4 = (const float4*)sp;
    // lane l: float4-group g = l&15 (components 4g..4g+3), block residue r = l>>4.
    // blocks b = r + 4k, k=0..63 -> each lane sums 64 float4s.
    const int g = l & 15;
    const int r = l >> 4;                          // 0..3
    float4 a0 = {0.f,0.f,0.f,0.f}, a1 = {0.f,0.f,0.f,0.f},
           a2 = {0.f,0.f,0.f,0.f}, a3 = {0.f,0.f,0.f,0.f};
    #pragma unroll
    for (int k = 0; k < 64; k += 4) {
        float4 v0 = sp4[(r + 4 * (k + 0)) * 16 + g];
        float4 v1 = sp4[(r + 4 * (k + 1)) * 16 + g];
        float4 v2 = sp4[(r + 4 * (k + 2)) * 16 + g];
        float4 v3 = sp4[(r + 4 * (k + 3)) * 16 + g];
        a0.x += v0.x; a0.y += v0.y; a0.z += v0.z; a0.w += v0.w;
        a1.x += v1.x; a1.y += v1.y; a1.z += v1.z; a1.w += v1.w;
        a2.x += v2.x; a2.y += v2.y; a2.z += v2.z; a2.w += v2.w;
        a3.x += v3.x; a3.y += v3.y; a3.z += v3.z; a3.w += v3.w;
    }
    float4 a;
    a.x = (a0.x + a1.x) + (a2.x + a3.x);
    a.y = (a0.y + a1.y) + (a2.y + a3.y);
    a.z = (a0.z + a1.z) + (a2.z + a3.z);
    a.w = (a0.w + a1.w) + (a2.w + a3.w);
    // fold the 4 residue groups (lanes l, l+16, l+32, l+48 share g)
    a.x += __shfl_xor(a.x, 16, 64); a.y += __shfl_xor(a.y, 16, 64);
    a.z += __shfl_xor(a.z, 16, 64); a.w += __shfl_xor(a.w, 16, 64);
    a.x += __shfl_xor(a.x, 32, 64); a.y += __shfl_xor(a.y, 32, 64);
    a.z += __shfl_xor(a.z, 32, 64); a.w += __shfl_xor(a.w, 32, 64);
    // lanes 0..15 hold S components 4g..4g+3 -> |S|^2 partial
    float s2 = (l < 16) ? (a.x * a.x + a.y * a.y + a.z * a.z + a.w * a.w) : 0.f;
    s2 += __shfl_xor(s2, 1, 64);
    s2 += __shfl_xor(s2, 2, 64);
    s2 += __shfl_xor(s2, 4, 64);
    s2 += __shfl_xor(s2, 8, 64);
    s2 += __shfl_xor(s2, 16, 64);
    s2 += __shfl_xor(s2, 32, 64);
    // cen partials: 256 scalars
    float cacc = (cp[l] + cp[l + 64]) + (cp[l + 128] + cp[l + 192]);
    cacc += __shfl_xor(cacc, 1, 64);
    cacc += __shfl_xor(cacc, 2, 64);
    cacc += __shfl_xor(cacc, 4, 64);
    cacc += __shfl_xor(cacc, 8, 64);
    cacc += __shfl_xor(cacc, 16, 64);
    cacc += __shfl_xor(cacc, 32, 64);
    if (l == 0) {
        double loss_cen = 0.5 * (double)cacc / (double)BATCH_N;
        double loss_ang = (double)s2 - (double)KCLS + (double)KCLS * (double)(KCLS - 1);
        out[0] = (float)(LAMB * (loss_cen + LAMB1 * loss_ang));
    }
}

extern "C" void kernel_launch(void* const* d_in, const int* in_sizes, int n_in,
                              void* d_out, int out_size, void* d_ws, size_t ws_size,
                              hipStream_t stream) {
    const int*   y       = (const int*)d_in[0];
    const float* feat    = (const float*)d_in[1];
    const float* centers = (const float*)d_in[2];
    float* out = (float*)d_out;
    float* sp  = (float*)d_ws;                       // NBLK*64 floats
    float* cp  = sp + NBLK * 64;                     // NBLK floats

    illoss_partials<<<NBLK, 256, 0, stream>>>(y, feat, centers, sp, cp);
    illoss_final<<<1, 64, 0, stream>>>(sp, cp, out);
}

// Round 10
// 11.388 us; speedup vs baseline: 3.5729x; 1.1557x over previous
//
#include <hip/hip_runtime.h>
#include <hip/hip_bf16.h>

#define KCLS 8192
#define DFEAT 64
#define BATCH_N 16384
#define LAMB 0.01
#define LAMB1 10.0

constexpr int NBLK_S = 64;    // S-path blocks: 256 waves x 8 iters x 4 rows  = 8192 rows
constexpr int NBLK_B = 128;   // cen-path blocks: 512 waves x 8 iters x 4 items = 16384 items

// ws layout: sp[NBLK_S*64] floats | cp[NBLK_B] floats
// Role-split grid (phases run in parallel on different CUs — measured faster
// than per-block fusion: R9 13.2us vs R2 11.7us) + light vectorized finalize.
__global__ __launch_bounds__(256) void illoss_partials(const int* __restrict__ y,
                                                       const float* __restrict__ feat,
                                                       const float* __restrict__ centers,
                                                       float* __restrict__ sp,
                                                       float* __restrict__ cp) {
    const int tid  = threadIdx.x;
    const int lane = tid & 63;
    const int wave = tid >> 6;
    const int blk  = blockIdx.x;
    const float4* __restrict__ centers4 = (const float4*)centers;

    if (blk < NBLK_S) {
        // ---- S partial: 32 rows per wave, 4 rows per float4 iter ----
        __shared__ float sacc[4][16][4];
        const int gwid = blk * 4 + wave;           // 0..255
        float ax = 0.f, ay = 0.f, az = 0.f, aw = 0.f;
        #pragma unroll
        for (int it = 0; it < 8; ++it) {
            const int row0 = gwid * 32 + it * 4;
            float4 v = centers4[row0 * 16 + lane];
            float ss = v.x * v.x + v.y * v.y + v.z * v.z + v.w * v.w;
            ss += __shfl_xor(ss, 1, 64);
            ss += __shfl_xor(ss, 2, 64);
            ss += __shfl_xor(ss, 4, 64);
            ss += __shfl_xor(ss, 8, 64);           // per 16-lane group: ||c||^2
            float inv = __frsqrt_rn(ss);
            ax += v.x * inv; ay += v.y * inv; az += v.z * inv; aw += v.w * inv;
        }
        ax += __shfl_xor(ax, 16, 64); ay += __shfl_xor(ay, 16, 64);
        az += __shfl_xor(az, 16, 64); aw += __shfl_xor(aw, 16, 64);
        ax += __shfl_xor(ax, 32, 64); ay += __shfl_xor(ay, 32, 64);
        az += __shfl_xor(az, 32, 64); aw += __shfl_xor(aw, 32, 64);
        if (lane < 16) {
            sacc[wave][lane][0] = ax; sacc[wave][lane][1] = ay;
            sacc[wave][lane][2] = az; sacc[wave][lane][3] = aw;
        }
        __syncthreads();
        if (tid < 64) {
            float s = sacc[0][tid >> 2][tid & 3] + sacc[1][tid >> 2][tid & 3]
                    + sacc[2][tid >> 2][tid & 3] + sacc[3][tid >> 2][tid & 3];
            sp[blk * 64 + tid] = s;
        }
    } else {
        // ---- cen partial: 32 items per wave, 4 items per float4 iter ----
        __shared__ float wacc[4];
        const int bblk = blk - NBLK_S;
        const int gwid = bblk * 4 + wave;          // 0..511
        const int base = gwid * 32;
        const float4* __restrict__ feat4 = (const float4*)feat;
        int cls[8];
        #pragma unroll
        for (int it = 0; it < 8; ++it) cls[it] = y[base + it * 4 + (lane >> 4)];
        float acc = 0.f;
        #pragma unroll
        for (int it = 0; it < 8; ++it) {
            float4 f = feat4[(base + it * 4) * 16 + lane];
            float4 c = centers4[cls[it] * 16 + (lane & 15)];
            float dx = f.x - c.x, dy = f.y - c.y, dz = f.z - c.z, dw = f.w - c.w;
            acc += dx * dx + dy * dy + dz * dz + dw * dw;
        }
        acc += __shfl_xor(acc, 1, 64);
        acc += __shfl_xor(acc, 2, 64);
        acc += __shfl_xor(acc, 4, 64);
        acc += __shfl_xor(acc, 8, 64);
        acc += __shfl_xor(acc, 16, 64);
        acc += __shfl_xor(acc, 32, 64);
        if (lane == 0) wacc[wave] = acc;
        __syncthreads();
        if (tid == 0) cp[bblk] = (wacc[0] + wacc[1]) + (wacc[2] + wacc[3]);
    }
}

// Single-wave finalize: 16 float4 + 2 scalar loads per lane.
__global__ __launch_bounds__(64) void illoss_final(const float* __restrict__ sp,
                                                   const float* __restrict__ cp,
                                                   float* __restrict__ out) {
    const int l = threadIdx.x;
    const float4* __restrict__ sp4 = (const float4*)sp;
    const int g = l & 15;                          // component group (4g..4g+3)
    const int r = l >> 4;                          // block residue 0..3
    float4 a0 = {0.f,0.f,0.f,0.f}, a1 = {0.f,0.f,0.f,0.f},
           a2 = {0.f,0.f,0.f,0.f}, a3 = {0.f,0.f,0.f,0.f};
    #pragma unroll
    for (int k = 0; k < 16; k += 4) {
        float4 v0 = sp4[(r + 4 * (k + 0)) * 16 + g];
        float4 v1 = sp4[(r + 4 * (k + 1)) * 16 + g];
        float4 v2 = sp4[(r + 4 * (k + 2)) * 16 + g];
        float4 v3 = sp4[(r + 4 * (k + 3)) * 16 + g];
        a0.x += v0.x; a0.y += v0.y; a0.z += v0.z; a0.w += v0.w;
        a1.x += v1.x; a1.y += v1.y; a1.z += v1.z; a1.w += v1.w;
        a2.x += v2.x; a2.y += v2.y; a2.z += v2.z; a2.w += v2.w;
        a3.x += v3.x; a3.y += v3.y; a3.z += v3.z; a3.w += v3.w;
    }
    float4 a;
    a.x = (a0.x + a1.x) + (a2.x + a3.x);
    a.y = (a0.y + a1.y) + (a2.y + a3.y);
    a.z = (a0.z + a1.z) + (a2.z + a3.z);
    a.w = (a0.w + a1.w) + (a2.w + a3.w);
    // fold residues (lanes l, l+16, l+32, l+48 share g)
    a.x += __shfl_xor(a.x, 16, 64); a.y += __shfl_xor(a.y, 16, 64);
    a.z += __shfl_xor(a.z, 16, 64); a.w += __shfl_xor(a.w, 16, 64);
    a.x += __shfl_xor(a.x, 32, 64); a.y += __shfl_xor(a.y, 32, 64);
    a.z += __shfl_xor(a.z, 32, 64); a.w += __shfl_xor(a.w, 32, 64);
    // lanes 0..15 hold S components 4g..4g+3 -> |S|^2 partial
    float s2 = (l < 16) ? (a.x * a.x + a.y * a.y + a.z * a.z + a.w * a.w) : 0.f;
    s2 += __shfl_xor(s2, 1, 64);
    s2 += __shfl_xor(s2, 2, 64);
    s2 += __shfl_xor(s2, 4, 64);
    s2 += __shfl_xor(s2, 8, 64);
    s2 += __shfl_xor(s2, 16, 64);
    s2 += __shfl_xor(s2, 32, 64);
    // cen partials: 128 scalars
    float cacc = cp[l] + cp[l + 64];
    cacc += __shfl_xor(cacc, 1, 64);
    cacc += __shfl_xor(cacc, 2, 64);
    cacc += __shfl_xor(cacc, 4, 64);
    cacc += __shfl_xor(cacc, 8, 64);
    cacc += __shfl_xor(cacc, 16, 64);
    cacc += __shfl_xor(cacc, 32, 64);
    if (l == 0) {
        double loss_cen = 0.5 * (double)cacc / (double)BATCH_N;
        double loss_ang = (double)s2 - (double)KCLS + (double)KCLS * (double)(KCLS - 1);
        out[0] = (float)(LAMB * (loss_cen + LAMB1 * loss_ang));
    }
}

extern "C" void kernel_launch(void* const* d_in, const int* in_sizes, int n_in,
                              void* d_out, int out_size, void* d_ws, size_t ws_size,
                              hipStream_t stream) {
    const int*   y       = (const int*)d_in[0];
    const float* feat    = (const float*)d_in[1];
    const float* centers = (const float*)d_in[2];
    float* out = (float*)d_out;
    float* sp  = (float*)d_ws;                        // NBLK_S*64 floats
    float* cp  = sp + NBLK_S * 64;                    // NBLK_B floats

    illoss_partials<<<NBLK_S + NBLK_B, 256, 0, stream>>>(y, feat, centers, sp, cp);
    illoss_final<<<1, 64, 0, stream>>>(sp, cp, out);
}